// Round 12
// baseline (432.292 us; speedup 1.0000x reference)
//
#include <hip/hip_runtime.h>
#include <math.h>

#define NNODES 20000
#define NEDGES 320000
#define FDIM 64
#define NHEAD 4
#define NGR 64
#define LATD 512
#define HF 256                // NHEAD*FDIM
#define NEP (NEDGES + NNODES) // edges incl. self loops = 340000
#define AGGIN 832             // FDIM*(1+3*NHEAD)
#define MPAD 20032

typedef float f32x4 __attribute__((ext_vector_type(4)));
typedef short bf16x8 __attribute__((ext_vector_type(8)));
typedef unsigned short u16x8 __attribute__((ext_vector_type(8)));

__device__ inline unsigned short f2bf(float f) {
    unsigned u = __float_as_uint(f);
    unsigned r = (u + 0x7FFF + ((u >> 16) & 1)) >> 16; // RNE
    return (unsigned short)r;
}
__device__ inline float bf2f(unsigned short h) {
    return __uint_as_float(((unsigned)h) << 16);
}
__device__ inline unsigned short f2h(float f) {
    _Float16 h = (_Float16)f;
    unsigned short u;
    __builtin_memcpy(&u, &h, 2);
    return u;
}
__device__ inline float h2f(unsigned short u) {
    _Float16 h;
    __builtin_memcpy(&h, &u, 2);
    return (float)h;
}

// ---------------- grids ----------------
#define EDGE_BLOCKS4 ((NEP + 1023) / 1024)  // 333, 4 edges/thread
#define CONV_N (HF * FDIM + 2 * HF * HF)    // 147456
#define CONV_BLOCKS ((CONV_N + 255) / 256)  // 576
#define ENC_BLOCKS (NNODES / 32)            // 625
#define GEMM_BLOCKS (NNODES / 32)           // 625
#define SLAB_BLOCKS (NNODES / 32)           // 625

// ---------------- prep: degree count (4 edges/thread) + weight splits --------
__global__ void prep_kernel(
    const int* __restrict__ ei, int* __restrict__ cnt,
    const float* __restrict__ W1, const float* __restrict__ W2, const float* __restrict__ W3,
    unsigned short* __restrict__ W1hi, unsigned short* __restrict__ W1lo,
    unsigned short* __restrict__ W2hi, unsigned short* __restrict__ W2lo,
    unsigned short* __restrict__ W3hi, unsigned short* __restrict__ W3lo)
{
    if (blockIdx.x < EDGE_BLOCKS4) {
        int i0 = blockIdx.x * 1024 + threadIdx.x;
#pragma unroll
        for (int u = 0; u < 4; u++) {
            int i = i0 + u * 256;
            if (i < NEDGES) {
                atomicAdd(&cnt[ei[NEDGES + i]], 1);
            } else if (i < NEP) {
                atomicAdd(&cnt[i - NEDGES], 1); // self loop
            }
        }
    } else {
        int i = (blockIdx.x - EDGE_BLOCKS4) * 256 + threadIdx.x;
        const int n1 = HF * FDIM, n2 = HF * HF;
        const float* src; unsigned short *hi, *lo; int j;
        if (i < n1) { src = W1; hi = W1hi; lo = W1lo; j = i; }
        else if (i < n1 + n2) { src = W2; hi = W2hi; lo = W2lo; j = i - n1; }
        else if (i < n1 + 2 * n2) { src = W3; hi = W3hi; lo = W3lo; j = i - n1 - n2; }
        else return;
        float f = src[j];
        unsigned short h = f2bf(f);
        hi[j] = h;
        lo[j] = f2bf(f - bf2f(h));
    }
}

// ---------------- CSR scan: 1024 threads ----------
__global__ __launch_bounds__(1024) void scan_deg(const int* __restrict__ deg, int* __restrict__ offs)
{
    __shared__ int wt[16];
    const int per = (NNODES + 1023) / 1024; // 20
    int t = threadIdx.x, lane = t & 63, w = t >> 6;
    int start = t * per;
    int end = start + per; if (end > NNODES) end = NNODES;
    int s = 0;
    for (int i = start; i < end; i++) s += deg[i];
    int pref = s;
#pragma unroll
    for (int m = 1; m < 64; m <<= 1) {
        int v = __shfl_up(pref, m, 64);
        if (lane >= m) pref += v;
    }
    if (lane == 63) wt[w] = pref;
    __syncthreads();
    int wadd = 0;
    for (int i = 0; i < w; i++) wadd += wt[i];
    int acc = wadd + pref - s; // exclusive prefix
    for (int i = start; i < end; i++) { offs[i] = acc; acc += deg[i]; }
    if (t == 1023) offs[NNODES] = NEP;
}

// ---------------- edge scatter (standalone, no LDS -> full occupancy) --------
__global__ void scatter_edges(const int* __restrict__ ei, const int* __restrict__ offs,
                              int* __restrict__ cnt2, int* __restrict__ csr_src)
{
    int i0 = blockIdx.x * 1024 + threadIdx.x;
    int sv[4], dv[4];
#pragma unroll
    for (int u = 0; u < 4; u++) {
        int i = i0 + u * 256;
        if (i < NEDGES) { sv[u] = ei[i]; dv[u] = ei[NEDGES + i]; }
        else if (i < NEP) { sv[u] = i - NEDGES; dv[u] = i - NEDGES; }
        else { sv[u] = -1; dv[u] = 0; }
    }
#pragma unroll
    for (int u = 0; u < 4; u++) {
        if (sv[u] >= 0) {
            int p = offs[dv[u]] + atomicAdd(&cnt2[dv[u]], 1);
            csr_src[p] = sv[u];
        }
    }
}

// ---------------- node encoder (standalone; keeps its LDS) ------------------
__global__ __launch_bounds__(256) void encode_n0(
    const float* __restrict__ sfeat, const float* __restrict__ bfeat,
    const float* __restrict__ smask, const float* __restrict__ bmask,
    const float* __restrict__ sW, const float* __restrict__ sb,
    const float* __restrict__ bW, const float* __restrict__ bb,
    const int* __restrict__ batch,
    unsigned short* __restrict__ nhi, unsigned short* __restrict__ nlo,
    int* __restrict__ g)
{
    __shared__ float wlds[64 * 132];
    int t = threadIdx.x;
#pragma unroll
    for (int it = 0; it < 8; it++) {
        int idx = it * 256 + t;
        int f = idx >> 5, k4 = idx & 31;
        float4 v = *(const float4*)(sW + f * 128 + k4 * 4);
        *(float4*)(&wlds[f * 132 + k4 * 4]) = v;
    }
    __syncthreads();

    int lane = t & 63, wave = t >> 6;
    int nb = blockIdx.x * 32 + wave * 8;

    float acc[8];
#pragma unroll
    for (int i = 0; i < 8; i++) acc[i] = 0.f;

    const float* xbase = sfeat + (size_t)nb * 128;
    for (int k4 = 0; k4 < 32; k4++) {
        float4 wv = *(const float4*)(&wlds[lane * 132 + k4 * 4]);
#pragma unroll
        for (int i = 0; i < 8; i++) {
            float4 xv = *(const float4*)(xbase + i * 128 + k4 * 4);
            acc[i] += xv.x * wv.x + xv.y * wv.y + xv.z * wv.z + xv.w * wv.w;
        }
    }

    float bwr[5];
#pragma unroll
    for (int k = 0; k < 5; k++) bwr[k] = bW[lane * 5 + k];
    float sbv = sb[lane], bbv = bb[lane];

    int curb = batch[nb];
    float m = 0.f;
#pragma unroll
    for (int i = 0; i < 8; i++) {
        int node = nb + i;
        float accb = 0.f;
#pragma unroll
        for (int k = 0; k < 5; k++) accb += bfeat[node * 5 + k] * bwr[k];
        float sv = fmaxf(acc[i] + sbv, 0.f);
        float bv = fmaxf(accb + bbv, 0.f);
        float val = sv * smask[node] + bv * bmask[node];
        unsigned short hb = f2bf(val);
        nhi[(size_t)node * FDIM + lane] = hb;
        nlo[(size_t)node * FDIM + lane] = f2bf(val - bf2f(hb));
        int b = batch[node];
        if (b != curb) {
            atomicMax(&g[curb * AGGIN + lane], __float_as_int(m));
            m = 0.f; curb = b;
        }
        m = fmaxf(m, val);
    }
    atomicMax(&g[curb * AGGIN + lane], __float_as_int(m));
}

// ---------------- MFMA GEMM + attn projections (bf16x3, batched loads) -------
// K-chunk = 64: 24 independent 16B loads feeding 48 MFMAs per chunk.
// sched_barrier(0) between the load batch and the MFMA batch prevents the
// compiler from sinking loads to just-before-use (round-11: VGPR=56 meant
// the dbuf collapsed and loads serialized; MfmaUtil 6%).
template <int K>
__global__ __launch_bounds__(256, 2) void gemm_attn_mfma(
    const unsigned short* __restrict__ xhi, const unsigned short* __restrict__ xlo,
    const unsigned short* __restrict__ Whi, const unsigned short* __restrict__ Wlo,
    const float* __restrict__ a_src, const float* __restrict__ a_dst,
    unsigned short* __restrict__ h, float* __restrict__ s, float* __restrict__ d)
{
    constexpr int NCHUNK = K / 64;
    int t = threadIdx.x, lane = t & 63, w = t >> 6;
    int colid = lane & 15, quad = lane >> 4;
    int nb = blockIdx.x * 32;

    f32x4 acc[2][4];
#pragma unroll
    for (int mt = 0; mt < 2; mt++)
#pragma unroll
        for (int nt = 0; nt < 4; nt++)
#pragma unroll
            for (int r = 0; r < 4; r++) acc[mt][nt][r] = 0.f;

#pragma unroll
    for (int c = 0; c < NCHUNK; c++) {
        const int kc = c * 64;
        bf16x8 bh[4][2], bl[4][2], ah[2][2], al[2][2];
        // ---- issue all 24 loads back-to-back ----
#pragma unroll
        for (int half = 0; half < 2; half++) {
#pragma unroll
            for (int mt = 0; mt < 2; mt++) {
                size_t aoff = (size_t)(nb + mt * 16 + colid) * K + kc + half * 32 + quad * 8;
                ah[mt][half] = *(const bf16x8*)&xhi[aoff];
                al[mt][half] = *(const bf16x8*)&xlo[aoff];
            }
#pragma unroll
            for (int nt = 0; nt < 4; nt++) {
                size_t boff = (size_t)(w * 64 + nt * 16 + colid) * K + kc + half * 32 + quad * 8;
                bh[nt][half] = *(const bf16x8*)&Whi[boff];
                bl[nt][half] = *(const bf16x8*)&Wlo[boff];
            }
        }
        __builtin_amdgcn_sched_barrier(0);
        // ---- 48 MFMAs ----
#pragma unroll
        for (int half = 0; half < 2; half++)
#pragma unroll
            for (int mt = 0; mt < 2; mt++)
#pragma unroll
                for (int nt = 0; nt < 4; nt++) {
                    acc[mt][nt] = __builtin_amdgcn_mfma_f32_16x16x32_bf16(ah[mt][half], bh[nt][half], acc[mt][nt], 0, 0, 0);
                    acc[mt][nt] = __builtin_amdgcn_mfma_f32_16x16x32_bf16(ah[mt][half], bl[nt][half], acc[mt][nt], 0, 0, 0);
                    acc[mt][nt] = __builtin_amdgcn_mfma_f32_16x16x32_bf16(al[mt][half], bh[nt][half], acc[mt][nt], 0, 0, 0);
                }
    }

    // ---- write h (fp16): C/D layout row=quad*4+r (node), col=colid ----
#pragma unroll
    for (int mt = 0; mt < 2; mt++) {
#pragma unroll
        for (int r = 0; r < 4; r++) {
            int node = nb + mt * 16 + quad * 4 + r;
#pragma unroll
            for (int nt = 0; nt < 4; nt++)
                h[(size_t)node * HF + w * 64 + nt * 16 + colid] = f2h(acc[mt][nt][r]);
        }
    }

    // ---- attention projections for head w ----
    float as_r[4], ad_r[4];
#pragma unroll
    for (int nt = 0; nt < 4; nt++) {
        as_r[nt] = a_src[w * 64 + nt * 16 + colid];
        ad_r[nt] = a_dst[w * 64 + nt * 16 + colid];
    }
#pragma unroll
    for (int mt = 0; mt < 2; mt++) {
#pragma unroll
        for (int r = 0; r < 4; r++) {
            float ps = 0.f, pd = 0.f;
#pragma unroll
            for (int nt = 0; nt < 4; nt++) {
                ps += acc[mt][nt][r] * as_r[nt];
                pd += acc[mt][nt][r] * ad_r[nt];
            }
#pragma unroll
            for (int m = 1; m < 16; m <<= 1) {
                ps += __shfl_xor(ps, m, 64);
                pd += __shfl_xor(pd, m, 64);
            }
            if (colid == 0) {
                int node = nb + mt * 16 + quad * 4 + r;
                s[(size_t)node * NHEAD + w] = ps;
                d[(size_t)node * NHEAD + w] = pd;
            }
        }
    }
}

// ---------------- GAT softmax + aggregate (one wave per node) ----------------
__global__ __launch_bounds__(256) void gat_aggr(
    const unsigned short* __restrict__ h, const float* __restrict__ s, const float* __restrict__ d,
    const int* __restrict__ offs, const int* __restrict__ csr_src,
    const float* __restrict__ bias,
    unsigned short* __restrict__ ohi, unsigned short* __restrict__ olo)
{
    int t = threadIdx.x;
    int lane = t & 63;
    int wv = t >> 6;
    int node = blockIdx.x * 4 + wv;
    int eh = lane >> 5;        // phase-B edge half
    int p = lane & 31;         // phase-B feature group
    int hd2 = p >> 3;          // phase-B head
    int f0 = p * 8;
    int lo = offs[node], hi = offs[node + 1];
    int deg = hi - lo;

    float a[8];
#pragma unroll
    for (int j = 0; j < 8; j++) a[j] = 0.f;
    float inv;

    if (deg <= 64) {
        int slot = lane >> 2, hd = lane & 3;
        float dn = d[(size_t)node * NHEAD + hd];
        float ev[4];
        int sv[4];
#pragma unroll
        for (int c = 0; c < 4; c++) {
            int k = c * 16 + slot;
            float e = -3.402823466e38f;
            int src = 0;
            if (k < deg) {
                src = csr_src[lo + k];
                float ee = s[(size_t)src * NHEAD + hd] + dn;
                e = fmaxf(ee, 0.2f * ee);
            }
            ev[c] = e; sv[c] = src;
        }
        float mx = fmaxf(fmaxf(ev[0], ev[1]), fmaxf(ev[2], ev[3]));
#pragma unroll
        for (int m = 4; m < 64; m <<= 1) mx = fmaxf(mx, __shfl_xor(mx, m, 64));
        float den = 0.f;
#pragma unroll
        for (int c = 0; c < 4; c++) {
            ev[c] = __expf(ev[c] - mx);  // invalid slots -> 0
            den += ev[c];
        }
#pragma unroll
        for (int m = 4; m < 64; m <<= 1) den += __shfl_xor(den, m, 64);

        inv = 1.f / __shfl(den, hd2);

        // phase B: 4 loads in flight (edges kk+2u+eh, u=0..3)
#pragma unroll
        for (int c = 0; c < 4; c++) {
            int base = c * 16;
            if (base >= deg) break;
            int n16 = deg - base; if (n16 > 16) n16 = 16;
            for (int kk = 0; kk < n16; kk += 8) {
                float ex[4]; int sr[4]; u16x8 hv[4];
#pragma unroll
                for (int u = 0; u < 4; u++) {
                    int sl = (kk + u * 2 + eh) * 4 + hd2;   // <= 63
                    ex[u] = __shfl(ev[c], sl);
                    sr[u] = __shfl(sv[c], sl);
                }
#pragma unroll
                for (int u = 0; u < 4; u++)
                    hv[u] = *(const u16x8*)(h + (size_t)sr[u] * HF + f0);
#pragma unroll
                for (int u = 0; u < 4; u++)
#pragma unroll
                    for (int j = 0; j < 8; j++) a[j] += ex[u] * h2f(hv[u][j]);
            }
        }
    } else {
        // fallback (deg > 64; astronomically rare, exact)
        float dn2 = d[(size_t)node * NHEAD + hd2];
        float mx = -3.402823466e38f;
        for (int i = lo; i < hi; i++) {
            int src = csr_src[i];
            float e = s[(size_t)src * NHEAD + hd2] + dn2;
            e = fmaxf(e, 0.2f * e);
            mx = fmaxf(mx, e);
        }
        float den = 0.f;
        for (int i = lo + eh; i < hi; i += 2) {
            int src = csr_src[i];
            float e = s[(size_t)src * NHEAD + hd2] + dn2;
            e = fmaxf(e, 0.2f * e);
            float ex = __expf(e - mx);
            den += ex;
            u16x8 hv = *(const u16x8*)(h + (size_t)src * HF + f0);
#pragma unroll
            for (int j = 0; j < 8; j++) a[j] += ex * h2f(hv[j]);
        }
        den += __shfl_xor(den, 32, 64);
        inv = 1.f / den;
    }

    // combine the two edge-halves
#pragma unroll
    for (int j = 0; j < 8; j++) a[j] += __shfl_xor(a[j], 32, 64);

    if (eh == 0) {
        float v[8];
#pragma unroll
        for (int j = 0; j < 8; j++) v[j] = fmaxf(a[j] * inv + bias[f0 + j], 0.f);
        ushort4 hb0, lb0, hb1, lb1;
        hb0.x = f2bf(v[0]); lb0.x = f2bf(v[0] - bf2f(hb0.x));
        hb0.y = f2bf(v[1]); lb0.y = f2bf(v[1] - bf2f(hb0.y));
        hb0.z = f2bf(v[2]); lb0.z = f2bf(v[2] - bf2f(hb0.z));
        hb0.w = f2bf(v[3]); lb0.w = f2bf(v[3] - bf2f(hb0.w));
        hb1.x = f2bf(v[4]); lb1.x = f2bf(v[4] - bf2f(hb1.x));
        hb1.y = f2bf(v[5]); lb1.y = f2bf(v[5] - bf2f(hb1.y));
        hb1.z = f2bf(v[6]); lb1.z = f2bf(v[6] - bf2f(hb1.z));
        hb1.w = f2bf(v[7]); lb1.w = f2bf(v[7] - bf2f(hb1.w));
        *(ushort4*)(ohi + (size_t)node * HF + f0) = hb0;
        *(ushort4*)(ohi + (size_t)node * HF + f0 + 4) = hb1;
        *(ushort4*)(olo + (size_t)node * HF + f0) = lb0;
        *(ushort4*)(olo + (size_t)node * HF + f0 + 4) = lb1;
    }
}

// ------- per-graph segment max from bf16 hi/lo pair (32-row slab) ----------
__global__ __launch_bounds__(256) void seg_max_slab_bf(
    const unsigned short* __restrict__ xhi, const unsigned short* __restrict__ xlo,
    const int* __restrict__ batch, int* __restrict__ g, int coloff)
{
    int f = threadIdx.x;
    int r0 = blockIdx.x * 32;        // 20000 = 625*32 exact
    int cur = batch[r0];
    float m = 0.f;
    for (int r = r0; r < r0 + 32; r += 4) {
        float v[4]; int bb[4];
#pragma unroll
        for (int i = 0; i < 4; i++) {
            size_t idx = (size_t)(r + i) * HF + f;
            v[i] = bf2f(xhi[idx]) + bf2f(xlo[idx]);
            bb[i] = batch[r + i];
        }
#pragma unroll
        for (int i = 0; i < 4; i++) {
            if (bb[i] != cur) {
                atomicMax(&g[cur * AGGIN + coloff + f], __float_as_int(m));
                m = 0.f; cur = bb[i];
            }
            m = fmaxf(m, v[i]);
        }
    }
    atomicMax(&g[cur * AGGIN + coloff + f], __float_as_int(m));
}

// ---------------- MLP head ----------------
__global__ __launch_bounds__(256) void mlp_latent(
    const float* __restrict__ g, const float* __restrict__ W, const float* __restrict__ b,
    float* __restrict__ latent)
{
    int idx = blockIdx.x * 256 + threadIdx.x; // 64*512
    int r = idx >> 9, c = idx & 511;
    const float4* gv = (const float4*)(g + (size_t)r * AGGIN);
    const float4* wv = (const float4*)(W + (size_t)c * AGGIN);
    float acc = 0.f;
#pragma unroll 4
    for (int k = 0; k < AGGIN / 4; k++) {
        float4 a = gv[k], w = wv[k];
        acc += a.x * w.x + a.y * w.y + a.z * w.z + a.w * w.w;
    }
    latent[idx] = acc + b[c];
}

__global__ __launch_bounds__(256) void mlp_head(
    const float* __restrict__ latent,
    const float* __restrict__ muW, const float* __restrict__ mub,
    const float* __restrict__ vW, const float* __restrict__ vb,
    float* __restrict__ out)
{
    int idx = blockIdx.x * 256 + threadIdx.x; // 2*64*512
    int half = idx >> 15;
    int j = idx & 32767;
    int r = j >> 9, c = j & 511;
    const float* W = half ? vW : muW;
    const float* bb = half ? vb : mub;
    const float4* lv = (const float4*)(latent + (size_t)r * LATD);
    const float4* wv = (const float4*)(W + (size_t)c * LATD);
    float acc = 0.f;
#pragma unroll 4
    for (int k = 0; k < LATD / 4; k++) {
        float4 a = lv[k], w = wv[k];
        acc += a.x * w.x + a.y * w.y + a.z * w.z + a.w * w.w;
    }
    out[idx] = acc + bb[c];
}

// ---------------- launch ----------------
static inline size_t align16(size_t x) { return (x + 15) & ~(size_t)15; }

extern "C" void kernel_launch(void* const* d_in, const int* in_sizes, int n_in,
                              void* d_out, int out_size, void* d_ws, size_t ws_size,
                              hipStream_t stream)
{
    const float* sfeat = (const float*)d_in[0];
    const float* bfeat = (const float*)d_in[1];
    const float* smask = (const float*)d_in[2];
    const float* bmask = (const float*)d_in[3];
    const int*   ei    = (const int*)d_in[4];
    const int*   batch = (const int*)d_in[5];
    const float* sW = (const float*)d_in[6];
    const float* sb = (const float*)d_in[7];
    const float* bW = (const float*)d_in[8];
    const float* bb = (const float*)d_in[9];
    const float* W1 = (const float*)d_in[10];
    const float* as1 = (const float*)d_in[11];
    const float* ad1 = (const float*)d_in[12];
    const float* b1 = (const float*)d_in[13];
    const float* W2 = (const float*)d_in[14];
    const float* as2 = (const float*)d_in[15];
    const float* ad2 = (const float*)d_in[16];
    const float* b2 = (const float*)d_in[17];
    const float* W3 = (const float*)d_in[18];
    const float* as3 = (const float*)d_in[19];
    const float* ad3 = (const float*)d_in[20];
    const float* b3 = (const float*)d_in[21];
    const float* aggW = (const float*)d_in[22];
    const float* aggb = (const float*)d_in[23];
    const float* muW = (const float*)d_in[24];
    const float* mub = (const float*)d_in[25];
    const float* vW = (const float*)d_in[26];
    const float* vb = (const float*)d_in[27];
    float* out = (float*)d_out;

    char* ws = (char*)d_ws;
    size_t off = 0;
    unsigned short* h = (unsigned short*)(ws + off); off = align16(off + (size_t)NNODES * HF * 2);
    unsigned short* Ahi = (unsigned short*)(ws + off); off = align16(off + (size_t)MPAD * HF * 2);
    unsigned short* Alo = (unsigned short*)(ws + off); off = align16(off + (size_t)MPAD * HF * 2);
    float* s  = (float*)(ws + off); off = align16(off + (size_t)NNODES * NHEAD * 4);
    float* d  = (float*)(ws + off); off = align16(off + (size_t)NNODES * NHEAD * 4);
    int* offs = (int*)(ws + off);   off = align16(off + (size_t)(NNODES + 1) * 4);
    // zero-init region: cnt | cnt2 | g (single memset)
    size_t zstart = off;
    int* cnt  = (int*)(ws + off);   off = align16(off + (size_t)NNODES * 4);
    int* cnt2 = (int*)(ws + off);   off = align16(off + (size_t)NNODES * 4);
    float* g  = (float*)(ws + off); off = align16(off + (size_t)NGR * AGGIN * 4);
    size_t zbytes = off - zstart;
    int* csr  = (int*)(ws + off);   off = align16(off + (size_t)NEP * 4);
    float* lat = (float*)(ws + off); off = align16(off + (size_t)NGR * LATD * 4);
    unsigned short* W1hi = (unsigned short*)(ws + off); off = align16(off + (size_t)HF * FDIM * 2);
    unsigned short* W1lo = (unsigned short*)(ws + off); off = align16(off + (size_t)HF * FDIM * 2);
    unsigned short* W2hi = (unsigned short*)(ws + off); off = align16(off + (size_t)HF * HF * 2);
    unsigned short* W2lo = (unsigned short*)(ws + off); off = align16(off + (size_t)HF * HF * 2);
    unsigned short* W3hi = (unsigned short*)(ws + off); off = align16(off + (size_t)HF * HF * 2);
    unsigned short* W3lo = (unsigned short*)(ws + off); off = align16(off + (size_t)HF * HF * 2);

    // one memset zeroes cnt, cnt2, g
    hipMemsetAsync(ws + zstart, 0, zbytes, stream);

    // degree count + weight splits (one grid)
    prep_kernel<<<EDGE_BLOCKS4 + CONV_BLOCKS, 256, 0, stream>>>(
        ei, cnt, W1, W2, W3, W1hi, W1lo, W2hi, W2lo, W3hi, W3lo);
    scan_deg<<<1, 1024, 0, stream>>>(cnt, offs);
    scatter_edges<<<EDGE_BLOCKS4, 256, 0, stream>>>(ei, offs, cnt2, csr);
    encode_n0<<<ENC_BLOCKS, 256, 0, stream>>>(
        sfeat, bfeat, smask, bmask, sW, sb, bW, bb, batch, Ahi, Alo, (int*)g);

    // layer 1
    gemm_attn_mfma<FDIM><<<GEMM_BLOCKS, 256, 0, stream>>>(
        Ahi, Alo, W1hi, W1lo, as1, ad1, h, s, d);
    gat_aggr<<<NNODES / 4, 256, 0, stream>>>(h, s, d, offs, csr, b1, Ahi, Alo);
    seg_max_slab_bf<<<SLAB_BLOCKS, 256, 0, stream>>>(Ahi, Alo, batch, (int*)g, FDIM);

    // layer 2
    gemm_attn_mfma<HF><<<GEMM_BLOCKS, 256, 0, stream>>>(
        Ahi, Alo, W2hi, W2lo, as2, ad2, h, s, d);
    gat_aggr<<<NNODES / 4, 256, 0, stream>>>(h, s, d, offs, csr, b2, Ahi, Alo);
    seg_max_slab_bf<<<SLAB_BLOCKS, 256, 0, stream>>>(Ahi, Alo, batch, (int*)g, FDIM + HF);

    // layer 3
    gemm_attn_mfma<HF><<<GEMM_BLOCKS, 256, 0, stream>>>(
        Ahi, Alo, W3hi, W3lo, as3, ad3, h, s, d);
    gat_aggr<<<NNODES / 4, 256, 0, stream>>>(h, s, d, offs, csr, b3, Ahi, Alo);
    seg_max_slab_bf<<<SLAB_BLOCKS, 256, 0, stream>>>(Ahi, Alo, batch, (int*)g, FDIM + 2 * HF);

    // MLP head
    mlp_latent<<<(NGR * LATD + 255) / 256, 256, 0, stream>>>(g, aggW, aggb, lat);
    mlp_head<<<(2 * NGR * LATD + 255) / 256, 256, 0, stream>>>(lat, muW, mub, vW, vb, out);
}

// Round 13
// 397.925 us; speedup vs baseline: 1.0864x; 1.0864x over previous
//
#include <hip/hip_runtime.h>
#include <math.h>

#define NNODES 20000
#define NEDGES 320000
#define FDIM 64
#define NHEAD 4
#define NGR 64
#define LATD 512
#define HF 256                // NHEAD*FDIM
#define NEP (NEDGES + NNODES) // edges incl. self loops = 340000
#define AGGIN 832             // FDIM*(1+3*NHEAD)
#define MPAD 20032

typedef float f32x4 __attribute__((ext_vector_type(4)));
typedef _Float16 f16x8 __attribute__((ext_vector_type(8)));
typedef unsigned short u16x8 __attribute__((ext_vector_type(8)));

__device__ inline unsigned short f2h(float f) {
    _Float16 h = (_Float16)f;
    unsigned short u;
    __builtin_memcpy(&u, &h, 2);
    return u;
}
__device__ inline float h2f(unsigned short u) {
    _Float16 h;
    __builtin_memcpy(&h, &u, 2);
    return (float)h;
}

// ---------------- grids ----------------
#define EDGE_BLOCKS4 ((NEP + 1023) / 1024)  // 333, 4 edges/thread
#define CONV_N (HF * FDIM + 2 * HF * HF)    // 147456
#define CONV_BLOCKS ((CONV_N + 255) / 256)  // 576
#define ENC_BLOCKS (NNODES / 32)            // 625
#define GEMM_BLOCKS (NNODES / 32)           // 625
#define SLAB_BLOCKS (NNODES / 32)           // 625

// ---------------- prep: degree count (4 edges/thread) + fp16 weight convert --
__global__ void prep_kernel(
    const int* __restrict__ ei, int* __restrict__ cnt,
    const float* __restrict__ W1, const float* __restrict__ W2, const float* __restrict__ W3,
    unsigned short* __restrict__ W1f, unsigned short* __restrict__ W2f,
    unsigned short* __restrict__ W3f)
{
    if (blockIdx.x < EDGE_BLOCKS4) {
        int i0 = blockIdx.x * 1024 + threadIdx.x;
#pragma unroll
        for (int u = 0; u < 4; u++) {
            int i = i0 + u * 256;
            if (i < NEDGES) {
                atomicAdd(&cnt[ei[NEDGES + i]], 1);
            } else if (i < NEP) {
                atomicAdd(&cnt[i - NEDGES], 1); // self loop
            }
        }
    } else {
        int i = (blockIdx.x - EDGE_BLOCKS4) * 256 + threadIdx.x;
        const int n1 = HF * FDIM, n2 = HF * HF;
        const float* src; unsigned short* dst; int j;
        if (i < n1) { src = W1; dst = W1f; j = i; }
        else if (i < n1 + n2) { src = W2; dst = W2f; j = i - n1; }
        else if (i < n1 + 2 * n2) { src = W3; dst = W3f; j = i - n1 - n2; }
        else return;
        dst[j] = f2h(src[j]);
    }
}

// ---------------- CSR scan: 1024 threads ----------
__global__ __launch_bounds__(1024) void scan_deg(const int* __restrict__ deg, int* __restrict__ offs)
{
    __shared__ int wt[16];
    const int per = (NNODES + 1023) / 1024; // 20
    int t = threadIdx.x, lane = t & 63, w = t >> 6;
    int start = t * per;
    int end = start + per; if (end > NNODES) end = NNODES;
    int s = 0;
    for (int i = start; i < end; i++) s += deg[i];
    int pref = s;
#pragma unroll
    for (int m = 1; m < 64; m <<= 1) {
        int v = __shfl_up(pref, m, 64);
        if (lane >= m) pref += v;
    }
    if (lane == 63) wt[w] = pref;
    __syncthreads();
    int wadd = 0;
    for (int i = 0; i < w; i++) wadd += wt[i];
    int acc = wadd + pref - s; // exclusive prefix
    for (int i = start; i < end; i++) { offs[i] = acc; acc += deg[i]; }
    if (t == 1023) offs[NNODES] = NEP;
}

// ---------------- edge scatter (no LDS -> full occupancy) --------
__global__ void scatter_edges(const int* __restrict__ ei, const int* __restrict__ offs,
                              int* __restrict__ cnt2, int* __restrict__ csr_src)
{
    int i0 = blockIdx.x * 1024 + threadIdx.x;
    int sv[4], dv[4];
#pragma unroll
    for (int u = 0; u < 4; u++) {
        int i = i0 + u * 256;
        if (i < NEDGES) { sv[u] = ei[i]; dv[u] = ei[NEDGES + i]; }
        else if (i < NEP) { sv[u] = i - NEDGES; dv[u] = i - NEDGES; }
        else { sv[u] = -1; dv[u] = 0; }
    }
#pragma unroll
    for (int u = 0; u < 4; u++) {
        if (sv[u] >= 0) {
            int p = offs[dv[u]] + atomicAdd(&cnt2[dv[u]], 1);
            csr_src[p] = sv[u];
        }
    }
}

// ---------------- node encoder (fp16 x0 out + fused n0 seg-max) --------------
__global__ __launch_bounds__(256) void encode_n0(
    const float* __restrict__ sfeat, const float* __restrict__ bfeat,
    const float* __restrict__ smask, const float* __restrict__ bmask,
    const float* __restrict__ sW, const float* __restrict__ sb,
    const float* __restrict__ bW, const float* __restrict__ bb,
    const int* __restrict__ batch,
    unsigned short* __restrict__ x0, int* __restrict__ g)
{
    __shared__ float wlds[64 * 132];
    int t = threadIdx.x;
#pragma unroll
    for (int it = 0; it < 8; it++) {
        int idx = it * 256 + t;
        int f = idx >> 5, k4 = idx & 31;
        float4 v = *(const float4*)(sW + f * 128 + k4 * 4);
        *(float4*)(&wlds[f * 132 + k4 * 4]) = v;
    }
    __syncthreads();

    int lane = t & 63, wave = t >> 6;
    int nb = blockIdx.x * 32 + wave * 8;

    float acc[8];
#pragma unroll
    for (int i = 0; i < 8; i++) acc[i] = 0.f;

    const float* xbase = sfeat + (size_t)nb * 128;
    for (int k4 = 0; k4 < 32; k4++) {
        float4 wv = *(const float4*)(&wlds[lane * 132 + k4 * 4]);
#pragma unroll
        for (int i = 0; i < 8; i++) {
            float4 xv = *(const float4*)(xbase + i * 128 + k4 * 4);
            acc[i] += xv.x * wv.x + xv.y * wv.y + xv.z * wv.z + xv.w * wv.w;
        }
    }

    float bwr[5];
#pragma unroll
    for (int k = 0; k < 5; k++) bwr[k] = bW[lane * 5 + k];
    float sbv = sb[lane], bbv = bb[lane];

    int curb = batch[nb];
    float m = 0.f;
#pragma unroll
    for (int i = 0; i < 8; i++) {
        int node = nb + i;
        float accb = 0.f;
#pragma unroll
        for (int k = 0; k < 5; k++) accb += bfeat[node * 5 + k] * bwr[k];
        float sv = fmaxf(acc[i] + sbv, 0.f);
        float bv = fmaxf(accb + bbv, 0.f);
        float val = sv * smask[node] + bv * bmask[node];
        x0[(size_t)node * FDIM + lane] = f2h(val);
        int b = batch[node];
        if (b != curb) {
            atomicMax(&g[curb * AGGIN + lane], __float_as_int(m));
            m = 0.f; curb = b;
        }
        m = fmaxf(m, val);
    }
    atomicMax(&g[curb * AGGIN + lane], __float_as_int(m));
}

// ---------------- fp16 MFMA GEMM + attn projections ----------
// Pure fp16 (no split): 3x fewer MFMAs and HALF the W/A bytes vs bf16x3.
// Round-12 diagnosis: gemm was W-re-read-bound at ~4 TB/s L3 aggregate
// (625 blocks x 256KB W-pair = 164 MB -> 42us). fp16 halves W to 82 MB.
template <int K>
__global__ __launch_bounds__(256, 2) void gemm_attn_mfma(
    const unsigned short* __restrict__ xf, const unsigned short* __restrict__ Wf,
    const float* __restrict__ a_src, const float* __restrict__ a_dst,
    unsigned short* __restrict__ h, float* __restrict__ s, float* __restrict__ d)
{
    constexpr int NCHUNK = K / 64;
    int t = threadIdx.x, lane = t & 63, w = t >> 6;
    int colid = lane & 15, quad = lane >> 4;
    int nb = blockIdx.x * 32;

    f32x4 acc[2][4];
#pragma unroll
    for (int mt = 0; mt < 2; mt++)
#pragma unroll
        for (int nt = 0; nt < 4; nt++)
#pragma unroll
            for (int r = 0; r < 4; r++) acc[mt][nt][r] = 0.f;

#pragma unroll
    for (int c = 0; c < NCHUNK; c++) {
        const int kc = c * 64;
        f16x8 ah[2][2], bh[4][2];
        // ---- issue all 12 loads back-to-back ----
#pragma unroll
        for (int half = 0; half < 2; half++) {
#pragma unroll
            for (int mt = 0; mt < 2; mt++) {
                size_t aoff = (size_t)(nb + mt * 16 + colid) * K + kc + half * 32 + quad * 8;
                ah[mt][half] = *(const f16x8*)&xf[aoff];
            }
#pragma unroll
            for (int nt = 0; nt < 4; nt++) {
                size_t boff = (size_t)(w * 64 + nt * 16 + colid) * K + kc + half * 32 + quad * 8;
                bh[nt][half] = *(const f16x8*)&Wf[boff];
            }
        }
        __builtin_amdgcn_sched_barrier(0);
        // ---- 16 MFMAs ----
#pragma unroll
        for (int half = 0; half < 2; half++)
#pragma unroll
            for (int mt = 0; mt < 2; mt++)
#pragma unroll
                for (int nt = 0; nt < 4; nt++)
                    acc[mt][nt] = __builtin_amdgcn_mfma_f32_16x16x32_f16(ah[mt][half], bh[nt][half], acc[mt][nt], 0, 0, 0);
    }

    // ---- write h (fp16): C/D layout row=quad*4+r (node), col=colid ----
#pragma unroll
    for (int mt = 0; mt < 2; mt++) {
#pragma unroll
        for (int r = 0; r < 4; r++) {
            int node = nb + mt * 16 + quad * 4 + r;
#pragma unroll
            for (int nt = 0; nt < 4; nt++)
                h[(size_t)node * HF + w * 64 + nt * 16 + colid] = f2h(acc[mt][nt][r]);
        }
    }

    // ---- attention projections for head w ----
    float as_r[4], ad_r[4];
#pragma unroll
    for (int nt = 0; nt < 4; nt++) {
        as_r[nt] = a_src[w * 64 + nt * 16 + colid];
        ad_r[nt] = a_dst[w * 64 + nt * 16 + colid];
    }
#pragma unroll
    for (int mt = 0; mt < 2; mt++) {
#pragma unroll
        for (int r = 0; r < 4; r++) {
            float ps = 0.f, pd = 0.f;
#pragma unroll
            for (int nt = 0; nt < 4; nt++) {
                ps += acc[mt][nt][r] * as_r[nt];
                pd += acc[mt][nt][r] * ad_r[nt];
            }
#pragma unroll
            for (int m = 1; m < 16; m <<= 1) {
                ps += __shfl_xor(ps, m, 64);
                pd += __shfl_xor(pd, m, 64);
            }
            if (colid == 0) {
                int node = nb + mt * 16 + quad * 4 + r;
                s[(size_t)node * NHEAD + w] = ps;
                d[(size_t)node * NHEAD + w] = pd;
            }
        }
    }
}

// ---------------- GAT softmax + aggregate (one wave per node) ----------------
// Output: single fp16 array (next layer's GEMM A operand / slab input).
__global__ __launch_bounds__(256) void gat_aggr(
    const unsigned short* __restrict__ h, const float* __restrict__ s, const float* __restrict__ d,
    const int* __restrict__ offs, const int* __restrict__ csr_src,
    const float* __restrict__ bias, unsigned short* __restrict__ out)
{
    int t = threadIdx.x;
    int lane = t & 63;
    int wv = t >> 6;
    int node = blockIdx.x * 4 + wv;
    int eh = lane >> 5;        // phase-B edge half
    int p = lane & 31;         // phase-B feature group
    int hd2 = p >> 3;          // phase-B head
    int f0 = p * 8;
    int lo = offs[node], hi = offs[node + 1];
    int deg = hi - lo;

    float a[8];
#pragma unroll
    for (int j = 0; j < 8; j++) a[j] = 0.f;
    float inv;

    if (deg <= 64) {
        int slot = lane >> 2, hd = lane & 3;
        float dn = d[(size_t)node * NHEAD + hd];
        float ev[4];
        int sv[4];
#pragma unroll
        for (int c = 0; c < 4; c++) {
            int k = c * 16 + slot;
            float e = -3.402823466e38f;
            int src = 0;
            if (k < deg) {
                src = csr_src[lo + k];
                float ee = s[(size_t)src * NHEAD + hd] + dn;
                e = fmaxf(ee, 0.2f * ee);
            }
            ev[c] = e; sv[c] = src;
        }
        float mx = fmaxf(fmaxf(ev[0], ev[1]), fmaxf(ev[2], ev[3]));
#pragma unroll
        for (int m = 4; m < 64; m <<= 1) mx = fmaxf(mx, __shfl_xor(mx, m, 64));
        float den = 0.f;
#pragma unroll
        for (int c = 0; c < 4; c++) {
            ev[c] = __expf(ev[c] - mx);  // invalid slots -> 0
            den += ev[c];
        }
#pragma unroll
        for (int m = 4; m < 64; m <<= 1) den += __shfl_xor(den, m, 64);

        inv = 1.f / __shfl(den, hd2);

        // phase B: 4 loads in flight (edges kk+2u+eh, u=0..3)
#pragma unroll
        for (int c = 0; c < 4; c++) {
            int base = c * 16;
            if (base >= deg) break;
            int n16 = deg - base; if (n16 > 16) n16 = 16;
            for (int kk = 0; kk < n16; kk += 8) {
                float ex[4]; int sr[4]; u16x8 hv[4];
#pragma unroll
                for (int u = 0; u < 4; u++) {
                    int sl = (kk + u * 2 + eh) * 4 + hd2;   // <= 63
                    ex[u] = __shfl(ev[c], sl);
                    sr[u] = __shfl(sv[c], sl);
                }
#pragma unroll
                for (int u = 0; u < 4; u++)
                    hv[u] = *(const u16x8*)(h + (size_t)sr[u] * HF + f0);
#pragma unroll
                for (int u = 0; u < 4; u++)
#pragma unroll
                    for (int j = 0; j < 8; j++) a[j] += ex[u] * h2f(hv[u][j]);
            }
        }
    } else {
        // fallback (deg > 64; astronomically rare, exact)
        float dn2 = d[(size_t)node * NHEAD + hd2];
        float mx = -3.402823466e38f;
        for (int i = lo; i < hi; i++) {
            int src = csr_src[i];
            float e = s[(size_t)src * NHEAD + hd2] + dn2;
            e = fmaxf(e, 0.2f * e);
            mx = fmaxf(mx, e);
        }
        float den = 0.f;
        for (int i = lo + eh; i < hi; i += 2) {
            int src = csr_src[i];
            float e = s[(size_t)src * NHEAD + hd2] + dn2;
            e = fmaxf(e, 0.2f * e);
            float ex = __expf(e - mx);
            den += ex;
            u16x8 hv = *(const u16x8*)(h + (size_t)src * HF + f0);
#pragma unroll
            for (int j = 0; j < 8; j++) a[j] += ex * h2f(hv[j]);
        }
        den += __shfl_xor(den, 32, 64);
        inv = 1.f / den;
    }

    // combine the two edge-halves
#pragma unroll
    for (int j = 0; j < 8; j++) a[j] += __shfl_xor(a[j], 32, 64);

    if (eh == 0) {
        u16x8 ov;
#pragma unroll
        for (int j = 0; j < 8; j++)
            ov[j] = f2h(fmaxf(a[j] * inv + bias[f0 + j], 0.f));
        *(u16x8*)(out + (size_t)node * HF + f0) = ov;
    }
}

// ------- per-graph segment max from fp16 (32-row slab, 4-row batched) --------
__global__ __launch_bounds__(256) void seg_max_slab_f16(
    const unsigned short* __restrict__ x, const int* __restrict__ batch,
    int* __restrict__ g, int coloff)
{
    int f = threadIdx.x;
    int r0 = blockIdx.x * 32;        // 20000 = 625*32 exact
    int cur = batch[r0];
    float m = 0.f;
    for (int r = r0; r < r0 + 32; r += 4) {
        float v[4]; int bb[4];
#pragma unroll
        for (int i = 0; i < 4; i++) {
            v[i] = h2f(x[(size_t)(r + i) * HF + f]);
            bb[i] = batch[r + i];
        }
#pragma unroll
        for (int i = 0; i < 4; i++) {
            if (bb[i] != cur) {
                atomicMax(&g[cur * AGGIN + coloff + f], __float_as_int(m));
                m = 0.f; cur = bb[i];
            }
            m = fmaxf(m, v[i]);
        }
    }
    atomicMax(&g[cur * AGGIN + coloff + f], __float_as_int(m));
}

// ---------------- MLP head ----------------
__global__ __launch_bounds__(256) void mlp_latent(
    const float* __restrict__ g, const float* __restrict__ W, const float* __restrict__ b,
    float* __restrict__ latent)
{
    int idx = blockIdx.x * 256 + threadIdx.x; // 64*512
    int r = idx >> 9, c = idx & 511;
    const float4* gv = (const float4*)(g + (size_t)r * AGGIN);
    const float4* wv = (const float4*)(W + (size_t)c * AGGIN);
    float acc = 0.f;
#pragma unroll 4
    for (int k = 0; k < AGGIN / 4; k++) {
        float4 a = gv[k], w = wv[k];
        acc += a.x * w.x + a.y * w.y + a.z * w.z + a.w * w.w;
    }
    latent[idx] = acc + b[c];
}

__global__ __launch_bounds__(256) void mlp_head(
    const float* __restrict__ latent,
    const float* __restrict__ muW, const float* __restrict__ mub,
    const float* __restrict__ vW, const float* __restrict__ vb,
    float* __restrict__ out)
{
    int idx = blockIdx.x * 256 + threadIdx.x; // 2*64*512
    int half = idx >> 15;
    int j = idx & 32767;
    int r = j >> 9, c = j & 511;
    const float* W = half ? vW : muW;
    const float* bb = half ? vb : mub;
    const float4* lv = (const float4*)(latent + (size_t)r * LATD);
    const float4* wv = (const float4*)(W + (size_t)c * LATD);
    float acc = 0.f;
#pragma unroll 4
    for (int k = 0; k < LATD / 4; k++) {
        float4 a = lv[k], w = wv[k];
        acc += a.x * w.x + a.y * w.y + a.z * w.z + a.w * w.w;
    }
    out[idx] = acc + bb[c];
}

// ---------------- launch ----------------
static inline size_t align16(size_t x) { return (x + 15) & ~(size_t)15; }

extern "C" void kernel_launch(void* const* d_in, const int* in_sizes, int n_in,
                              void* d_out, int out_size, void* d_ws, size_t ws_size,
                              hipStream_t stream)
{
    const float* sfeat = (const float*)d_in[0];
    const float* bfeat = (const float*)d_in[1];
    const float* smask = (const float*)d_in[2];
    const float* bmask = (const float*)d_in[3];
    const int*   ei    = (const int*)d_in[4];
    const int*   batch = (const int*)d_in[5];
    const float* sW = (const float*)d_in[6];
    const float* sb = (const float*)d_in[7];
    const float* bW = (const float*)d_in[8];
    const float* bb = (const float*)d_in[9];
    const float* W1 = (const float*)d_in[10];
    const float* as1 = (const float*)d_in[11];
    const float* ad1 = (const float*)d_in[12];
    const float* b1 = (const float*)d_in[13];
    const float* W2 = (const float*)d_in[14];
    const float* as2 = (const float*)d_in[15];
    const float* ad2 = (const float*)d_in[16];
    const float* b2 = (const float*)d_in[17];
    const float* W3 = (const float*)d_in[18];
    const float* as3 = (const float*)d_in[19];
    const float* ad3 = (const float*)d_in[20];
    const float* b3 = (const float*)d_in[21];
    const float* aggW = (const float*)d_in[22];
    const float* aggb = (const float*)d_in[23];
    const float* muW = (const float*)d_in[24];
    const float* mub = (const float*)d_in[25];
    const float* vW = (const float*)d_in[26];
    const float* vb = (const float*)d_in[27];
    float* out = (float*)d_out;

    char* ws = (char*)d_ws;
    size_t off = 0;
    unsigned short* h  = (unsigned short*)(ws + off); off = align16(off + (size_t)NNODES * HF * 2);
    unsigned short* x0 = (unsigned short*)(ws + off); off = align16(off + (size_t)MPAD * FDIM * 2);
    unsigned short* xA = (unsigned short*)(ws + off); off = align16(off + (size_t)MPAD * HF * 2);
    float* s  = (float*)(ws + off); off = align16(off + (size_t)NNODES * NHEAD * 4);
    float* d  = (float*)(ws + off); off = align16(off + (size_t)NNODES * NHEAD * 4);
    int* offs = (int*)(ws + off);   off = align16(off + (size_t)(NNODES + 1) * 4);
    // zero-init region: cnt | cnt2 | g (single memset)
    size_t zstart = off;
    int* cnt  = (int*)(ws + off);   off = align16(off + (size_t)NNODES * 4);
    int* cnt2 = (int*)(ws + off);   off = align16(off + (size_t)NNODES * 4);
    float* g  = (float*)(ws + off); off = align16(off + (size_t)NGR * AGGIN * 4);
    size_t zbytes = off - zstart;
    int* csr  = (int*)(ws + off);   off = align16(off + (size_t)NEP * 4);
    float* lat = (float*)(ws + off); off = align16(off + (size_t)NGR * LATD * 4);
    unsigned short* W1f = (unsigned short*)(ws + off); off = align16(off + (size_t)HF * FDIM * 2);
    unsigned short* W2f = (unsigned short*)(ws + off); off = align16(off + (size_t)HF * HF * 2);
    unsigned short* W3f = (unsigned short*)(ws + off); off = align16(off + (size_t)HF * HF * 2);

    // one memset zeroes cnt, cnt2, g
    hipMemsetAsync(ws + zstart, 0, zbytes, stream);

    // degree count + fp16 weight convert (one grid)
    prep_kernel<<<EDGE_BLOCKS4 + CONV_BLOCKS, 256, 0, stream>>>(
        ei, cnt, W1, W2, W3, W1f, W2f, W3f);
    scan_deg<<<1, 1024, 0, stream>>>(cnt, offs);
    scatter_edges<<<EDGE_BLOCKS4, 256, 0, stream>>>(ei, offs, cnt2, csr);
    encode_n0<<<ENC_BLOCKS, 256, 0, stream>>>(
        sfeat, bfeat, smask, bmask, sW, sb, bW, bb, batch, x0, (int*)g);

    // layer 1
    gemm_attn_mfma<FDIM><<<GEMM_BLOCKS, 256, 0, stream>>>(
        x0, W1f, as1, ad1, h, s, d);
    gat_aggr<<<NNODES / 4, 256, 0, stream>>>(h, s, d, offs, csr, b1, xA);
    seg_max_slab_f16<<<SLAB_BLOCKS, 256, 0, stream>>>(xA, batch, (int*)g, FDIM);

    // layer 2
    gemm_attn_mfma<HF><<<GEMM_BLOCKS, 256, 0, stream>>>(
        xA, W2f, as2, ad2, h, s, d);
    gat_aggr<<<NNODES / 4, 256, 0, stream>>>(h, s, d, offs, csr, b2, xA);
    seg_max_slab_f16<<<SLAB_BLOCKS, 256, 0, stream>>>(xA, batch, (int*)g, FDIM + HF);

    // layer 3
    gemm_attn_mfma<HF><<<GEMM_BLOCKS, 256, 0, stream>>>(
        xA, W3f, as3, ad3, h, s, d);
    gat_aggr<<<NNODES / 4, 256, 0, stream>>>(h, s, d, offs, csr, b3, xA);
    seg_max_slab_f16<<<SLAB_BLOCKS, 256, 0, stream>>>(xA, batch, (int*)g, FDIM + 2 * HF);

    // MLP head
    mlp_latent<<<(NGR * LATD + 255) / 256, 256, 0, stream>>>(g, aggW, aggb, lat);
    mlp_head<<<(2 * NGR * LATD + 255) / 256, 256, 0, stream>>>(lat, muW, mub, vW, vb, out);
}